// Round 4
// baseline (246.604 us; speedup 1.0000x reference)
//
#include <hip/hip_runtime.h>
#include <math.h>

// LIF recurrence: v_t = v_{t-1}*decay*(1-z_{t-1}) + x_t ; z_t = (v_t > 0.3)
// x [B=128,T=2048,H=128] f32; out [B,T,H] f32 spikes.
//
// R4: barrier-free producer-consumer pipeline (hipBLASLt-style wave roles).
// 256 blocks x 256 threads (1 block/CU). Per block:
//   w0: computes the 64 serial chains (tile-by-tile from LDS x-ring)
//   w1: x-loader, even tiles; w3: x-loader, odd tiles (global_load_lds,
//       inline-asm s_waitcnt vmcnt(16) -> never a full drain)
//   w2: z-storer (LDS z-ring -> coalesced dwordx4 stores, fire-and-forget)
// Handshake via monotonic counters in LDS (single writer each, volatile).
// No __syncthreads in the loop -> VM ops stay in flight across tiles.

constexpr int Bdim = 128;
constexpr int Tdim = 2048;
constexpr int Hdim = 128;
constexpr int HW   = 64;           // chains per block
constexpr int Ut   = 64;           // timesteps per tile (16 KB)
constexpr int NT   = Tdim / Ut;    // 32 tiles
constexpr int NX   = 5;            // x-ring depth (80 KB)
constexpr int NZ   = 3;            // z-ring depth (48 KB)
constexpr float VTH = 0.3f;

// flags: [0]=xl_done_even [1]=xl_done_odd [2]=xc_done [3]=zc_done [4]=zs_done

typedef const __attribute__((address_space(1))) void* gptr_t;
typedef __attribute__((address_space(3))) void* lptr_t;

__device__ __forceinline__ void cfence() { asm volatile("" ::: "memory"); }

__global__ __launch_bounds__(256) void lif_kernel(
    const float* __restrict__ x,
    const float* __restrict__ v0,
    const float* __restrict__ z0,
    const float* __restrict__ decay_raw,
    float* __restrict__ out)
{
    __shared__ float xbuf[NX][Ut][HW];
    __shared__ float zbuf[NZ][Ut][HW];
    __shared__ int   flags[8];

    volatile int* vf = (volatile int*)flags;

    const int tid  = threadIdx.x;
    const int wave = tid >> 6;
    const int lane = tid & 63;
    const int blk  = blockIdx.x;
    const int b    = blk >> 1;
    const int h0   = (blk & 1) * HW;

    if (tid < 8) flags[tid] = 0;
    __syncthreads();                       // init only; nothing in flight yet

    const float* xbase = x   + (size_t)b * Tdim * Hdim + h0;
    float*       obase = out + (size_t)b * Tdim * Hdim + h0;
    // DMA/flush lane mapping (verified in R2/R3): inst j covers tile rows
    // [4j,4j+4): lane i -> row 4j+(i>>4), float col (i&15)*4.
    const int sub = (lane >> 4) * Hdim + (lane & 15) * 4;

    if (wave == 1 || wave == 3) {
        // ---------------- x loaders ----------------
        const int par = (wave == 1) ? 0 : 1;
        for (int i = 0; i < NT / 2; ++i) {
            const int k = 2 * i + par;
            while (vf[2] < k - NX + 1) __builtin_amdgcn_s_sleep(2);  // slot free
            cfence();
            const float* g = xbase + (size_t)k * Ut * Hdim + sub;
            float* lbase = &xbuf[k % NX][0][0];
            #pragma unroll
            for (int j = 0; j < Ut / 4; ++j) {
                __builtin_amdgcn_global_load_lds(
                    (gptr_t)(const void*)(g + (size_t)(4 * j) * Hdim),
                    (lptr_t)(void*)(lbase + 4 * j * HW),
                    16, 0, 0);
            }
            // <=16 outstanding => all own tiles <= i-1 fully in LDS
            asm volatile("s_waitcnt vmcnt(16)" ::: "memory");
            if (lane == 0) vf[par] = i;    // i own-tiles complete
        }
        asm volatile("s_waitcnt vmcnt(0)" ::: "memory");
        if (lane == 0) vf[par] = NT / 2;
    } else if (wave == 0) {
        // ---------------- compute ----------------
        const float decay = 1.0f / (1.0f + expf(-decay_raw[h0 + lane]));
        float v = v0[b * Hdim + h0 + lane];
        float z = z0[b * Hdim + h0 + lane];

        for (int k = 0; k < NT; ++k) {
            const int need = (k >> 1) + 1;
            while (vf[k & 1] < need) __builtin_amdgcn_s_sleep(2);   // x tile ready
            while (vf[4] < k - NZ + 1) __builtin_amdgcn_s_sleep(2); // z slot free
            cfence();
            const int xb = k % NX, zb = k % NZ;
            #pragma unroll 16
            for (int t = 0; t < Ut; ++t) {
                const float xv = xbuf[xb][t][lane];
                const float a  = v * decay + 0.0f;     // keep mul separate:
                const float s  = a + xv;               // mul-then-add rounding
                v = (z > 0.5f) ? xv : s;               // z=1 -> exactly x
                z = (v > VTH) ? 1.0f : 0.0f;
                zbuf[zb][t][lane] = z;
            }
            asm volatile("s_waitcnt lgkmcnt(0)" ::: "memory");  // z visible
            if (lane == 0) { vf[3] = k + 1; vf[2] = k + 1; }
        }
    } else {
        // ---------------- z storer ----------------
        for (int k = 0; k < NT; ++k) {
            while (vf[3] < k + 1) __builtin_amdgcn_s_sleep(2);
            cfence();
            const int zb = k % NZ;
            float* op = obase + (size_t)k * Ut * Hdim;
            #pragma unroll
            for (int s = 0; s < Ut / 4; ++s) {
                const int row = 4 * s + (lane >> 4);
                const int col = (lane & 15) * 4;
                const float4 vv = *(const float4*)&zbuf[zb][row][col];
                *(float4*)(op + (size_t)row * Hdim + col) = vv;
            }
            cfence();                       // reads consumed -> slot free
            if (lane == 0) vf[4] = k + 1;
            // throttle outstanding stores (<= ~2 tiles), never full drain
            asm volatile("s_waitcnt vmcnt(16)" ::: "memory");
        }
    }
}

extern "C" void kernel_launch(void* const* d_in, const int* in_sizes, int n_in,
                              void* d_out, int out_size, void* d_ws, size_t ws_size,
                              hipStream_t stream) {
    const float* x         = (const float*)d_in[0];
    const float* v0        = (const float*)d_in[1];
    const float* z0        = (const float*)d_in[2];
    const float* decay_raw = (const float*)d_in[3];
    float* out = (float*)d_out;

    lif_kernel<<<Bdim * Hdim / HW, 256, 0, stream>>>(x, v0, z0, decay_raw, out);
}